// Round 2
// baseline (2105.887 us; speedup 1.0000x reference)
//
#include <hip/hip_runtime.h>
#include <math.h>

#define NB 4
#define NL 1024
#define ND 1024
#define NH 16
#define HD 64

// ---------------- repack: w[o][i][k] -> wt[k][i][o] ----------------
__global__ __launch_bounds__(256) void repack_kernel(
    const float* __restrict__ w0, const float* __restrict__ w1,
    const float* __restrict__ w2, const float* __restrict__ w3,
    float* __restrict__ wt_all)
{
  const float* w = (blockIdx.z == 0) ? w0 : (blockIdx.z == 1) ? w1 :
                   (blockIdx.z == 2) ? w2 : w3;
  float* wt = wt_all + (size_t)blockIdx.z * 3 * ND * ND;
  __shared__ __align__(16) float lds[64 * 193];
  const int o0 = blockIdx.y * 64;
  const int i0 = blockIdx.x * 64;
  const int tid = threadIdx.x;
  // load: rows of 192 contiguous floats (w[o, i0:i0+64, 0:3])
  for (int idx = tid; idx < 64 * 192; idx += 256) {
    int oo = idx / 192, j = idx - oo * 192;
    lds[oo * 193 + j] = w[(size_t)(o0 + oo) * (ND * 3) + i0 * 3 + j];
  }
  __syncthreads();
  // store: coalesced over o
  for (int idx = tid; idx < 64 * 192; idx += 256) {
    int k = idx >> 12;          // 0..2
    int r = idx & 4095;
    int ii = r >> 6, oo = r & 63;
    wt[(size_t)k * ND * ND + (size_t)(i0 + ii) * ND + (o0 + oo)] =
        lds[oo * 193 + ii * 3 + k];
  }
}

// ---------------- conv-as-GEMM ----------------
// Y[b,o,l] = bias[o] + sum_{koff,i} X[b, l+koff-1, i] * Wt[koff][i][o]
// X: [B, L, D] row-major (channels contiguous).
// out_mode 0: Y layout [B, H, L, HD]  (for q/k/v -> attention)
// out_mode 1: Y layout [B, L, D]      (final output)
__global__ __launch_bounds__(256) void conv_gemm_kernel(
    const float* __restrict__ X, const float* __restrict__ Wt,
    const float* __restrict__ bias, float* __restrict__ Y, int out_mode)
{
  __shared__ __align__(16) float As[32 * 68];  // [kk][mm]
  __shared__ __align__(16) float Bs[32 * 68];  // [kk][nn]
  const int n0 = blockIdx.x * 64;
  const int m0 = blockIdx.y * 64;     // m = b*L + l; 64 | L so one batch per tile
  const int b  = m0 >> 10;
  const int l0 = m0 & (NL - 1);
  const int tid = threadIdx.x;
  const int ty = tid >> 4, tx = tid & 15;

  float acc[4][4] = {};

  const int arow = tid >> 3;          // 0..31  (m row within tile)
  const int acol = (tid & 7) << 2;    // 0,4,..,28 (k col)
  const int brow = tid >> 4;          // 0..15  (kk)
  const int bcol = (tid & 15) << 2;   // 0..60  (n col)

  for (int koff = 0; koff < 3; ++koff) {
    const float* Wk = Wt + (size_t)koff * ND * ND;
    for (int i0 = 0; i0 < ND; i0 += 32) {
      // ---- load A tile (transposed into [kk][mm]) ----
#pragma unroll
      for (int rr = 0; rr < 2; ++rr) {
        int mm = arow + rr * 32;
        int l = l0 + mm + koff - 1;
        float4 v = make_float4(0.f, 0.f, 0.f, 0.f);
        if (l >= 0 && l < NL)
          v = *(const float4*)&X[((size_t)(b << 10) + l) * ND + i0 + acol];
        As[(acol + 0) * 68 + mm] = v.x;
        As[(acol + 1) * 68 + mm] = v.y;
        As[(acol + 2) * 68 + mm] = v.z;
        As[(acol + 3) * 68 + mm] = v.w;
      }
      // ---- load B tile ----
#pragma unroll
      for (int rr = 0; rr < 2; ++rr) {
        int kk = brow + rr * 16;
        *(float4*)&Bs[kk * 68 + bcol] =
            *(const float4*)&Wk[(size_t)(i0 + kk) * ND + n0 + bcol];
      }
      __syncthreads();
      // ---- inner product ----
#pragma unroll
      for (int kk = 0; kk < 32; ++kk) {
        float4 a4 = *(const float4*)&As[kk * 68 + ty * 4];
        float4 b4 = *(const float4*)&Bs[kk * 68 + tx * 4];
        float av[4] = {a4.x, a4.y, a4.z, a4.w};
        float bv[4] = {b4.x, b4.y, b4.z, b4.w};
#pragma unroll
        for (int i = 0; i < 4; ++i)
#pragma unroll
          for (int j = 0; j < 4; ++j) acc[i][j] += av[i] * bv[j];
      }
      __syncthreads();
    }
  }

  // ---- epilogue ----
  float4 bi = *(const float4*)&bias[n0 + tx * 4];
  float bvv[4] = {bi.x, bi.y, bi.z, bi.w};
#pragma unroll
  for (int r = 0; r < 4; ++r) {
    int l = l0 + ty * 4 + r;
    float4 v;
    v.x = acc[r][0] + bvv[0];
    v.y = acc[r][1] + bvv[1];
    v.z = acc[r][2] + bvv[2];
    v.w = acc[r][3] + bvv[3];
    if (out_mode == 0) {
      int h = n0 >> 6;
      int dd = (n0 & 63) + tx * 4;
      *(float4*)&Y[((((size_t)b * NH + h) * NL) + l) * HD + dd] = v;
    } else {
      *(float4*)&Y[((size_t)(b << 10) + l) * ND + n0 + tx * 4] = v;
    }
  }
}

// ---------------- fused attention (flash-style, fp32) ----------------
// qT/kT/vT: [B, H, L, HD].  AO: [B, L, D] with AO[b, i, h*64+dd] = out[b,h,dd,i]
__global__ __launch_bounds__(256) void attn_kernel(
    const float* __restrict__ qT, const float* __restrict__ kT,
    const float* __restrict__ vT, const int* __restrict__ kpm,
    const float* __restrict__ amask, float* __restrict__ AO)
{
  const int m0 = blockIdx.x * 64;
  const int h  = blockIdx.y;
  const int b  = blockIdx.z;
  __shared__ __align__(16) float Qs[64 * 68];   // [dd][r]
  __shared__ __align__(16) float KPs[64 * 68];  // K as [dd][c]; later P as [c][r]
  __shared__ __align__(16) float Vs[64 * 68];   // [j][cd]
  __shared__ float alphaS[64];
  __shared__ float rowlS[64];
  const int tid = threadIdx.x;
  const int ty = tid >> 4, tx = tid & 15;
  const float scale = 0.125f;  // 1/sqrt(64)
  const size_t baseQ = (((size_t)b * NH + h) * NL) * HD;

  // tile-load indexing: 64x64 floats = 1024 float4; 256 thr x 4 iters
  const int rrow = tid >> 4;          // 0..15
  const int rcol = (tid & 15) << 2;   // 0..60

  // load Q tile transposed -> Qs[dd][r]
#pragma unroll
  for (int rr = 0; rr < 4; ++rr) {
    int r = rrow + rr * 16;
    float4 v = *(const float4*)&qT[baseQ + (size_t)(m0 + r) * HD + rcol];
    Qs[(rcol + 0) * 68 + r] = v.x;
    Qs[(rcol + 1) * 68 + r] = v.y;
    Qs[(rcol + 2) * 68 + r] = v.z;
    Qs[(rcol + 3) * 68 + r] = v.w;
  }

  float acc[4][4] = {};
  float m_r = -INFINITY, l_r = 0.0f;  // valid for tid < 64

  for (int n0 = 0; n0 < NL; n0 += 64) {
    // load K (transposed -> KPs[dd][c]) and V (direct -> Vs[c][dd])
#pragma unroll
    for (int rr = 0; rr < 4; ++rr) {
      int c = rrow + rr * 16;
      float4 kv = *(const float4*)&kT[baseQ + (size_t)(n0 + c) * HD + rcol];
      KPs[(rcol + 0) * 68 + c] = kv.x;
      KPs[(rcol + 1) * 68 + c] = kv.y;
      KPs[(rcol + 2) * 68 + c] = kv.z;
      KPs[(rcol + 3) * 68 + c] = kv.w;
      float4 vv = *(const float4*)&vT[baseQ + (size_t)(n0 + c) * HD + rcol];
      *(float4*)&Vs[c * 68 + rcol] = vv;
    }
    __syncthreads();

    // S = Q . K^T  (4x4 per thread)
    float s[4][4] = {};
#pragma unroll 8
    for (int dd = 0; dd < 64; ++dd) {
      float4 qa = *(const float4*)&Qs[dd * 68 + ty * 4];
      float4 ka = *(const float4*)&KPs[dd * 68 + tx * 4];
      float qv[4] = {qa.x, qa.y, qa.z, qa.w};
      float kv[4] = {ka.x, ka.y, ka.z, ka.w};
#pragma unroll
      for (int i = 0; i < 4; ++i)
#pragma unroll
        for (int j = 0; j < 4; ++j) s[i][j] += qv[i] * kv[j];
    }
    __syncthreads();  // everyone done reading K before overwriting with P

    // mask + write P^T into KPs as [c][r]
#pragma unroll
    for (int i = 0; i < 4; ++i) {
      int gr = m0 + ty * 4 + i;
#pragma unroll
      for (int j = 0; j < 4; ++j) {
        int gc = n0 + tx * 4 + j;
        float val = s[i][j] * scale + amask[(size_t)gr * NL + gc];
        if (kpm[b * NL + gc] != 0) val = -INFINITY;
        KPs[(tx * 4 + j) * 68 + (ty * 4 + i)] = val;
      }
    }
    __syncthreads();

    // online softmax per row (threads 0..63)
    if (tid < 64) {
      const int r = tid;
      float tmax = -INFINITY;
      for (int j = 0; j < 64; ++j) tmax = fmaxf(tmax, KPs[j * 68 + r]);
      float newm = fmaxf(m_r, tmax);
      float alpha;
      float rowsum = 0.0f;
      if (newm == -INFINITY) {
        alpha = 1.0f;
        for (int j = 0; j < 64; ++j) KPs[j * 68 + r] = 0.0f;
      } else {
        alpha = __expf(m_r - newm);
        for (int j = 0; j < 64; ++j) {
          float p = __expf(KPs[j * 68 + r] - newm);
          KPs[j * 68 + r] = p;
          rowsum += p;
        }
      }
      m_r = newm;
      l_r = l_r * alpha + rowsum;
      alphaS[r] = alpha;
    }
    __syncthreads();

    // rescale acc and accumulate P.V
#pragma unroll
    for (int i = 0; i < 4; ++i) {
      float a = alphaS[ty * 4 + i];
#pragma unroll
      for (int j = 0; j < 4; ++j) acc[i][j] *= a;
    }
#pragma unroll 8
    for (int jk = 0; jk < 64; ++jk) {
      float4 pa = *(const float4*)&KPs[jk * 68 + ty * 4];
      float4 va = *(const float4*)&Vs[jk * 68 + tx * 4];
      float pv[4] = {pa.x, pa.y, pa.z, pa.w};
      float vv[4] = {va.x, va.y, va.z, va.w};
#pragma unroll
      for (int i = 0; i < 4; ++i)
#pragma unroll
        for (int j = 0; j < 4; ++j) acc[i][j] += pv[i] * vv[j];
    }
    __syncthreads();
  }

  if (tid < 64) rowlS[tid] = l_r;
  __syncthreads();

#pragma unroll
  for (int i = 0; i < 4; ++i) {
    int gr = m0 + ty * 4 + i;
    float inv = 1.0f / rowlS[ty * 4 + i];
    float4 v;
    v.x = acc[i][0] * inv;
    v.y = acc[i][1] * inv;
    v.z = acc[i][2] * inv;
    v.w = acc[i][3] * inv;
    *(float4*)&AO[((size_t)(b << 10) + gr) * ND + h * HD + tx * 4] = v;
  }
}

// ---------------- launch ----------------
extern "C" void kernel_launch(void* const* d_in, const int* in_sizes, int n_in,
                              void* d_out, int out_size, void* d_ws, size_t ws_size,
                              hipStream_t stream) {
  (void)in_sizes; (void)n_in; (void)out_size; (void)ws_size;
  const float* query = (const float*)d_in[0];
  const float* key_  = (const float*)d_in[1];
  const float* value = (const float*)d_in[2];
  const int*   kpm   = (const int*)d_in[3];
  const float* amask = (const float*)d_in[4];
  const float* q_w = (const float*)d_in[5];
  const float* q_b = (const float*)d_in[6];
  const float* k_w = (const float*)d_in[7];
  const float* k_b = (const float*)d_in[8];
  const float* v_w = (const float*)d_in[9];
  const float* v_b = (const float*)d_in[10];
  const float* o_w = (const float*)d_in[11];
  const float* o_b = (const float*)d_in[12];
  float* out = (float*)d_out;

  float* ws = (float*)d_ws;
  const size_t WT_ONE = (size_t)3 * ND * ND;       // 3,145,728 floats per tensor
  const size_t NBL    = (size_t)NB * NL * ND;      // 4,194,304 floats
  float* Wt = ws;                                  // [4][3][D][D]
  float* qT = ws + 4 * WT_ONE;
  float* kT = qT + NBL;
  float* vT = kT + NBL;
  float* AO = ws;  // alias over Wt[0..1] (dead after q/k/v convs; Wt_o untouched)

  repack_kernel<<<dim3(16, 16, 4), 256, 0, stream>>>(q_w, k_w, v_w, o_w, Wt);
  conv_gemm_kernel<<<dim3(16, 64), 256, 0, stream>>>(query, Wt + 0 * WT_ONE, q_b, qT, 0);
  conv_gemm_kernel<<<dim3(16, 64), 256, 0, stream>>>(key_,  Wt + 1 * WT_ONE, k_b, kT, 0);
  conv_gemm_kernel<<<dim3(16, 64), 256, 0, stream>>>(value, Wt + 2 * WT_ONE, v_b, vT, 0);
  attn_kernel<<<dim3(16, 16, 4), 256, 0, stream>>>(qT, kT, vT, kpm, amask, AO);
  conv_gemm_kernel<<<dim3(16, 64), 256, 0, stream>>>(AO, Wt + 3 * WT_ONE, o_b, out, 1);
}

// Round 3
// 1193.273 us; speedup vs baseline: 1.7648x; 1.7648x over previous
//
#include <hip/hip_runtime.h>
#include <math.h>

#define NB 4
#define NL 1024
#define ND 1024
#define NH 16
#define HD 64

typedef __attribute__((ext_vector_type(8))) short bf16x8;
typedef __attribute__((ext_vector_type(4))) float f32x4;

static __device__ __forceinline__ unsigned short f32_to_bf16(float f) {
  unsigned u = __float_as_uint(f);
  u += 0x7FFFu + ((u >> 16) & 1u);   // RNE
  return (unsigned short)(u >> 16);
}
static __device__ __forceinline__ float bf16_to_f32(unsigned short s) {
  return __uint_as_float(((unsigned)s) << 16);
}

// ---------------- weight convert: w[o][i][k] fp32 -> Wb hi/lo [koff][o][i] bf16 ----------------
__global__ __launch_bounds__(256) void wcvt_kernel(
    const float* __restrict__ w0, const float* __restrict__ w1,
    const float* __restrict__ w2, const float* __restrict__ w3,
    unsigned short* __restrict__ wb)
{
  const int t = blockIdx.y;   // tensor 0..3
  const int o = blockIdx.x;   // 0..1023
  const float* w = (t == 0) ? w0 : (t == 1) ? w1 : (t == 2) ? w2 : w3;
  unsigned short* hi = wb + (size_t)t * 6 * (1u << 20);
  unsigned short* lo = hi + 3 * (1u << 20);
  const int tid = threadIdx.x;
  float v[12];
  const float* src = w + (size_t)o * (ND * 3) + tid * 12;
#pragma unroll
  for (int j = 0; j < 3; ++j) {
    float4 f = *(const float4*)(src + j * 4);
    v[j * 4 + 0] = f.x; v[j * 4 + 1] = f.y; v[j * 4 + 2] = f.z; v[j * 4 + 3] = f.w;
  }
  // v[ii*3 + k] = w[o][4*tid + ii][k]
#pragma unroll
  for (int k = 0; k < 3; ++k) {
    unsigned short hh[4], ll[4];
#pragma unroll
    for (int ii = 0; ii < 4; ++ii) {
      float x = v[ii * 3 + k];
      unsigned short h = f32_to_bf16(x);
      float r = x - bf16_to_f32(h);
      hh[ii] = h; ll[ii] = f32_to_bf16(r);
    }
    size_t dst = (size_t)k * (ND * ND) + (size_t)o * ND + tid * 4;
    *(ushort4*)&hi[dst] = make_ushort4(hh[0], hh[1], hh[2], hh[3]);
    *(ushort4*)&lo[dst] = make_ushort4(ll[0], ll[1], ll[2], ll[3]);
  }
}

// ---------------- conv-as-GEMM via split-bf16 MFMA ----------------
// C[m,n] = bias[n] + sum_{koff,i} X[b, l0+mm+koff-1, i] * W[koff][i][n]
// Wb: bf16 [koff][o=n][i] (K-contiguous = MFMA B-operand friendly)
// out_mode 0: Y [B,H,L,HD]; out_mode 1: Y [B,L,D]
__global__ __launch_bounds__(256) void conv_mfma_kernel(
    const float* X0, const float* X1, const float* X2,
    const unsigned short* __restrict__ wb,
    const float* b0, const float* b1, const float* b2,
    float* Y0, float* Y1, float* Y2,
    int wtensor0, int out_mode)
{
  const int z = blockIdx.z;
  const float* X    = (z == 0) ? X0 : (z == 1) ? X1 : X2;
  const float* bias = (z == 0) ? b0 : (z == 1) ? b1 : b2;
  float* Y          = (z == 0) ? Y0 : (z == 1) ? Y1 : Y2;
  const unsigned short* Wh = wb + (size_t)(wtensor0 + z) * 6 * (1u << 20);
  const unsigned short* Wl = Wh + 3 * (1u << 20);

  __shared__ unsigned short Ah[128 * 40];  // padded stride 40 (2-way banks, free)
  __shared__ unsigned short Al[128 * 40];
  __shared__ unsigned short Bh[128 * 32];  // unpadded (global_load_lds), chunk-swizzled
  __shared__ unsigned short Bl[128 * 32];

  const int tid  = threadIdx.x;
  const int lane = tid & 63;
  const int wave = tid >> 6;
  const int wm = (wave >> 1) * 64;
  const int wn = (wave & 1) * 64;
  const int n0 = blockIdx.x * 128;
  const int m0 = blockIdx.y * 128;
  const int b  = m0 >> 10;
  const int l0 = m0 & (NL - 1);

  f32x4 acc[4][4] = {};

  // A staging: 4 rounds; thread covers row r = rr*32 + (tid>>3), k-cols (tid&7)*4
  const int ar  = tid >> 3;
  const int akc = (tid & 7) * 4;

  // B staging (global_load_lds): lane -> LDS row r16=lane>>2, chunk slot cs=lane&3.
  // Slot (r16, cs) must hold global k-chunk (cs - (r16>>1)) & 3  [bank-spread swizzle]
  const int r16 = lane >> 2;
  const int cs  = lane & 3;
  const int src_chunk = (cs - (r16 >> 1)) & 3;

  // fragment read indices
  const int mrow = lane & 15;
  const int quad = lane >> 4;
  const int bswz = ((quad + (mrow >> 1)) & 3) * 8;  // swizzled chunk (ushort offset)

  for (int koff = 0; koff < 3; ++koff) {
    for (int i0 = 0; i0 < ND; i0 += 32) {
      // ---- stage B tile (128 rows x 32 k) via async 16B loads; wave w: segments 2w,2w+1
#pragma unroll
      for (int s = 0; s < 2; ++s) {
        const int seg = wave * 2 + s;
        const size_t goff = (size_t)koff * (ND * ND) +
                            (size_t)(n0 + seg * 16 + r16) * ND + i0 + src_chunk * 8;
        __builtin_amdgcn_global_load_lds(
            (const __attribute__((address_space(1))) unsigned int*)(Wh + goff),
            (__attribute__((address_space(3))) unsigned int*)&Bh[seg * 512], 16, 0, 0);
        __builtin_amdgcn_global_load_lds(
            (const __attribute__((address_space(1))) unsigned int*)(Wl + goff),
            (__attribute__((address_space(3))) unsigned int*)&Bl[seg * 512], 16, 0, 0);
      }
      // ---- stage A tile (128 rows x 32 k) fp32->hi/lo with boundary predication
#pragma unroll
      for (int rr = 0; rr < 4; ++rr) {
        const int r = rr * 32 + ar;
        const int l = l0 + r + koff - 1;
        float4 f = make_float4(0.f, 0.f, 0.f, 0.f);
        if ((unsigned)l < NL)
          f = *(const float4*)&X[((size_t)(b << 10) + l) * ND + i0 + akc];
        float xs[4] = {f.x, f.y, f.z, f.w};
        unsigned short hh[4], ll[4];
#pragma unroll
        for (int ii = 0; ii < 4; ++ii) {
          unsigned short h = f32_to_bf16(xs[ii]);
          hh[ii] = h;
          ll[ii] = f32_to_bf16(xs[ii] - bf16_to_f32(h));
        }
        *(ushort4*)&Ah[r * 40 + akc] = make_ushort4(hh[0], hh[1], hh[2], hh[3]);
        *(ushort4*)&Al[r * 40 + akc] = make_ushort4(ll[0], ll[1], ll[2], ll[3]);
      }
      __syncthreads();

      // ---- compute: 48 MFMAs / wave / K-step
      bf16x8 ah[4], al[4];
#pragma unroll
      for (int mi = 0; mi < 4; ++mi) {
        const int row = wm + mi * 16 + mrow;
        ah[mi] = *(const bf16x8*)&Ah[row * 40 + quad * 8];
        al[mi] = *(const bf16x8*)&Al[row * 40 + quad * 8];
      }
#pragma unroll
      for (int ni = 0; ni < 4; ++ni) {
        const int row = wn + ni * 16 + mrow;
        bf16x8 bh = *(const bf16x8*)&Bh[row * 32 + bswz];
        bf16x8 bl = *(const bf16x8*)&Bl[row * 32 + bswz];
#pragma unroll
        for (int mi = 0; mi < 4; ++mi) {
          acc[mi][ni] = __builtin_amdgcn_mfma_f32_16x16x32_bf16(ah[mi], bh, acc[mi][ni], 0, 0, 0);
          acc[mi][ni] = __builtin_amdgcn_mfma_f32_16x16x32_bf16(ah[mi], bl, acc[mi][ni], 0, 0, 0);
          acc[mi][ni] = __builtin_amdgcn_mfma_f32_16x16x32_bf16(al[mi], bh, acc[mi][ni], 0, 0, 0);
        }
      }
      __syncthreads();
    }
  }

  // ---- epilogue: C/D frag (col=lane&15, row=quad*4+reg), add bias, store fp32
#pragma unroll
  for (int ni = 0; ni < 4; ++ni) {
    const int n = n0 + wn + ni * 16 + mrow;
    const float bv = bias[n];
#pragma unroll
    for (int mi = 0; mi < 4; ++mi) {
      const int mbase = m0 + wm + mi * 16 + quad * 4;
      f32x4 v = acc[mi][ni];
#pragma unroll
      for (int r = 0; r < 4; ++r) {
        const int l = (mbase + r) & (NL - 1);
        const float val = v[r] + bv;
        if (out_mode == 0) {
          const int h = n >> 6, dd = n & 63;
          Y[(((size_t)b * NH + h) * NL + l) * HD + dd] = val;
        } else {
          Y[((size_t)(b << 10) + l) * ND + n] = val;
        }
      }
    }
  }
}

// ---------------- fused attention (flash-style, fp32) — unchanged from R2 ----------------
__global__ __launch_bounds__(256) void attn_kernel(
    const float* __restrict__ qT, const float* __restrict__ kT,
    const float* __restrict__ vT, const int* __restrict__ kpm,
    const float* __restrict__ amask, float* __restrict__ AO)
{
  const int m0 = blockIdx.x * 64;
  const int h  = blockIdx.y;
  const int b  = blockIdx.z;
  __shared__ __align__(16) float Qs[64 * 68];
  __shared__ __align__(16) float KPs[64 * 68];
  __shared__ __align__(16) float Vs[64 * 68];
  __shared__ float alphaS[64];
  __shared__ float rowlS[64];
  const int tid = threadIdx.x;
  const int ty = tid >> 4, tx = tid & 15;
  const float scale = 0.125f;
  const size_t baseQ = (((size_t)b * NH + h) * NL) * HD;

  const int rrow = tid >> 4;
  const int rcol = (tid & 15) << 2;

#pragma unroll
  for (int rr = 0; rr < 4; ++rr) {
    int r = rrow + rr * 16;
    float4 v = *(const float4*)&qT[baseQ + (size_t)(m0 + r) * HD + rcol];
    Qs[(rcol + 0) * 68 + r] = v.x;
    Qs[(rcol + 1) * 68 + r] = v.y;
    Qs[(rcol + 2) * 68 + r] = v.z;
    Qs[(rcol + 3) * 68 + r] = v.w;
  }

  float acc[4][4] = {};
  float m_r = -INFINITY, l_r = 0.0f;

  for (int n0 = 0; n0 < NL; n0 += 64) {
#pragma unroll
    for (int rr = 0; rr < 4; ++rr) {
      int c = rrow + rr * 16;
      float4 kv = *(const float4*)&kT[baseQ + (size_t)(n0 + c) * HD + rcol];
      KPs[(rcol + 0) * 68 + c] = kv.x;
      KPs[(rcol + 1) * 68 + c] = kv.y;
      KPs[(rcol + 2) * 68 + c] = kv.z;
      KPs[(rcol + 3) * 68 + c] = kv.w;
      float4 vv = *(const float4*)&vT[baseQ + (size_t)(n0 + c) * HD + rcol];
      *(float4*)&Vs[c * 68 + rcol] = vv;
    }
    __syncthreads();

    float s[4][4] = {};
#pragma unroll 8
    for (int dd = 0; dd < 64; ++dd) {
      float4 qa = *(const float4*)&Qs[dd * 68 + ty * 4];
      float4 ka = *(const float4*)&KPs[dd * 68 + tx * 4];
      float qv[4] = {qa.x, qa.y, qa.z, qa.w};
      float kv[4] = {ka.x, ka.y, ka.z, ka.w};
#pragma unroll
      for (int i = 0; i < 4; ++i)
#pragma unroll
        for (int j = 0; j < 4; ++j) s[i][j] += qv[i] * kv[j];
    }
    __syncthreads();

#pragma unroll
    for (int i = 0; i < 4; ++i) {
      int gr = m0 + ty * 4 + i;
#pragma unroll
      for (int j = 0; j < 4; ++j) {
        int gc = n0 + tx * 4 + j;
        float val = s[i][j] * scale + amask[(size_t)gr * NL + gc];
        if (kpm[b * NL + gc] != 0) val = -INFINITY;
        KPs[(tx * 4 + j) * 68 + (ty * 4 + i)] = val;
      }
    }
    __syncthreads();

    if (tid < 64) {
      const int r = tid;
      float tmax = -INFINITY;
      for (int j = 0; j < 64; ++j) tmax = fmaxf(tmax, KPs[j * 68 + r]);
      float newm = fmaxf(m_r, tmax);
      float alpha;
      float rowsum = 0.0f;
      if (newm == -INFINITY) {
        alpha = 1.0f;
        for (int j = 0; j < 64; ++j) KPs[j * 68 + r] = 0.0f;
      } else {
        alpha = __expf(m_r - newm);
        for (int j = 0; j < 64; ++j) {
          float p = __expf(KPs[j * 68 + r] - newm);
          KPs[j * 68 + r] = p;
          rowsum += p;
        }
      }
      m_r = newm;
      l_r = l_r * alpha + rowsum;
      alphaS[r] = alpha;
    }
    __syncthreads();

#pragma unroll
    for (int i = 0; i < 4; ++i) {
      float a = alphaS[ty * 4 + i];
#pragma unroll
      for (int j = 0; j < 4; ++j) acc[i][j] *= a;
    }
#pragma unroll 8
    for (int jk = 0; jk < 64; ++jk) {
      float4 pa = *(const float4*)&KPs[jk * 68 + ty * 4];
      float4 va = *(const float4*)&Vs[jk * 68 + tx * 4];
      float pv[4] = {pa.x, pa.y, pa.z, pa.w};
      float vv[4] = {va.x, va.y, va.z, va.w};
#pragma unroll
      for (int i = 0; i < 4; ++i)
#pragma unroll
        for (int j = 0; j < 4; ++j) acc[i][j] += pv[i] * vv[j];
    }
    __syncthreads();
  }

  if (tid < 64) rowlS[tid] = l_r;
  __syncthreads();

#pragma unroll
  for (int i = 0; i < 4; ++i) {
    int gr = m0 + ty * 4 + i;
    float inv = 1.0f / rowlS[ty * 4 + i];
    float4 v;
    v.x = acc[i][0] * inv;
    v.y = acc[i][1] * inv;
    v.z = acc[i][2] * inv;
    v.w = acc[i][3] * inv;
    *(float4*)&AO[((size_t)(b << 10) + gr) * ND + h * HD + tx * 4] = v;
  }
}

// ---------------- launch ----------------
extern "C" void kernel_launch(void* const* d_in, const int* in_sizes, int n_in,
                              void* d_out, int out_size, void* d_ws, size_t ws_size,
                              hipStream_t stream) {
  (void)in_sizes; (void)n_in; (void)out_size; (void)ws_size;
  const float* query = (const float*)d_in[0];
  const float* key_  = (const float*)d_in[1];
  const float* value = (const float*)d_in[2];
  const int*   kpm   = (const int*)d_in[3];
  const float* amask = (const float*)d_in[4];
  const float* q_w = (const float*)d_in[5];
  const float* q_b = (const float*)d_in[6];
  const float* k_w = (const float*)d_in[7];
  const float* k_b = (const float*)d_in[8];
  const float* v_w = (const float*)d_in[9];
  const float* v_b = (const float*)d_in[10];
  const float* o_w = (const float*)d_in[11];
  const float* o_b = (const float*)d_in[12];
  float* out = (float*)d_out;

  // ws layout (bytes): Wb[4 tensors][hi|lo] ushort = 50,331,648 B;
  // then qT,kT,vT fp32 (3 x 16,777,216 B). Total 100,663,296 B (same as R1/R2).
  unsigned short* Wb = (unsigned short*)d_ws;
  float* qT = (float*)((char*)d_ws + (size_t)50331648);
  float* kT = qT + (size_t)NB * NL * ND;
  float* vT = kT + (size_t)NB * NL * ND;
  float* AO = (float*)d_ws;  // aliases Wb_q/Wb_k (dead after qkv convs); 16.78MB <= 25.17MB

  wcvt_kernel<<<dim3(1024, 4), 256, 0, stream>>>(q_w, k_w, v_w, o_w, Wb);
  conv_mfma_kernel<<<dim3(8, 32, 3), 256, 0, stream>>>(
      query, key_, value, Wb, q_b, k_b, v_b, qT, kT, vT, 0, 0);
  attn_kernel<<<dim3(16, 16, 4), 256, 0, stream>>>(qT, kT, vT, kpm, amask, AO);
  conv_mfma_kernel<<<dim3(8, 32, 1), 256, 0, stream>>>(
      AO, AO, AO, Wb, o_b, o_b, o_b, out, out, out, 3, 1);
}

// Round 4
// 805.866 us; speedup vs baseline: 2.6132x; 1.4807x over previous
//
#include <hip/hip_runtime.h>
#include <math.h>

#define NB 4
#define NL 1024
#define ND 1024
#define NH 16
#define HD 64

typedef __attribute__((ext_vector_type(8))) short bf16x8;
typedef __attribute__((ext_vector_type(4))) float f32x4;

static __device__ __forceinline__ unsigned short f32_to_bf16(float f) {
  unsigned u = __float_as_uint(f);
  u += 0x7FFFu + ((u >> 16) & 1u);   // RNE
  return (unsigned short)(u >> 16);
}
static __device__ __forceinline__ float bf16_to_f32(unsigned short s) {
  return __uint_as_float(((unsigned)s) << 16);
}

// trunc-split 8 fp32 -> hi bf16x8 (top 16 bits) + lo bf16x8 (trunc of residual).
// residual after hi+lo reconstruct ~2^-16 rel; dropped Al*Bl term ~2^-16.
static __device__ __forceinline__ void split8(float4 a, float4 b, bf16x8* hi, bf16x8* lo) {
  unsigned u[8] = {__float_as_uint(a.x), __float_as_uint(a.y),
                   __float_as_uint(a.z), __float_as_uint(a.w),
                   __float_as_uint(b.x), __float_as_uint(b.y),
                   __float_as_uint(b.z), __float_as_uint(b.w)};
  union { unsigned p[4]; bf16x8 v; } H, L;
#pragma unroll
  for (int p = 0; p < 4; ++p) {
    unsigned u0 = u[2 * p], u1 = u[2 * p + 1];
    H.p[p] = __builtin_amdgcn_perm(u1, u0, 0x07060302u);  // [hi16(u1)|hi16(u0)]
    unsigned l0 = __float_as_uint(__uint_as_float(u0) - __uint_as_float(u0 & 0xFFFF0000u));
    unsigned l1 = __float_as_uint(__uint_as_float(u1) - __uint_as_float(u1 & 0xFFFF0000u));
    L.p[p] = __builtin_amdgcn_perm(l1, l0, 0x07060302u);
  }
  *hi = H.v; *lo = L.v;
}

// ---------------- weight convert: w[o][i][k] fp32 -> Wb hi/lo [koff][o][i] bf16 ----------------
__global__ __launch_bounds__(256) void wcvt_kernel(
    const float* __restrict__ w0, const float* __restrict__ w1,
    const float* __restrict__ w2, const float* __restrict__ w3,
    unsigned short* __restrict__ wb)
{
  const int t = blockIdx.y;
  const int o = blockIdx.x;
  const float* w = (t == 0) ? w0 : (t == 1) ? w1 : (t == 2) ? w2 : w3;
  unsigned short* hi = wb + (size_t)t * 6 * (1u << 20);
  unsigned short* lo = hi + 3 * (1u << 20);
  const int tid = threadIdx.x;
  float v[12];
  const float* src = w + (size_t)o * (ND * 3) + tid * 12;
#pragma unroll
  for (int j = 0; j < 3; ++j) {
    float4 f = *(const float4*)(src + j * 4);
    v[j * 4 + 0] = f.x; v[j * 4 + 1] = f.y; v[j * 4 + 2] = f.z; v[j * 4 + 3] = f.w;
  }
#pragma unroll
  for (int k = 0; k < 3; ++k) {
    unsigned short hh[4], ll[4];
#pragma unroll
    for (int ii = 0; ii < 4; ++ii) {
      float x = v[ii * 3 + k];
      unsigned short h = f32_to_bf16(x);
      float r = x - bf16_to_f32(h);
      hh[ii] = h; ll[ii] = f32_to_bf16(r);
    }
    size_t dst = (size_t)k * (ND * ND) + (size_t)o * ND + tid * 4;
    *(ushort4*)&hi[dst] = make_ushort4(hh[0], hh[1], hh[2], hh[3]);
    *(ushort4*)&lo[dst] = make_ushort4(ll[0], ll[1], ll[2], ll[3]);
  }
}

// ---------------- conv-as-GEMM, all staging via global_load_lds ----------------
// mode 0: z = tensor (q/k/v), koff loop 0..2, +bias, out [B,H,L,HD]
// mode 1: z = koff (split-K o-conv), no bias, out partial P[z] in [B*L, D]
__global__ __launch_bounds__(256, 3) void conv_mfma2(
    const float* X0, const float* X1, const float* X2,
    const unsigned short* __restrict__ wb,
    const float* b0, const float* b1, const float* b2,
    float* Y0, float* Y1, float* Y2, int mode)
{
  __shared__ float Af[128 * 32];            // fp32 A tile, chunk-swizzled rows
  __shared__ unsigned short Bh[128 * 32];   // bf16 hi, chunk-swizzled
  __shared__ unsigned short Bl[128 * 32];

  const int tid = threadIdx.x, lane = tid & 63, wave = tid >> 6;
  // XCD swizzle: each XCD (lin%8) gets an n-pair x m-half; W slab + X tile fit L2
  const int lin = blockIdx.x + 8 * (blockIdx.y + 32 * blockIdx.z);
  const int g = lin & 7, t = lin >> 3;
  const int nb = (g & 3) * 2 + (t & 1);
  const int mb = (g >> 2) * 16 + ((t >> 1) & 15);
  const int z  = t >> 5;
  const int n0 = nb * 128, m0 = mb * 128;
  const int b = m0 >> 10, l0v = m0 & (NL - 1);

  const float* X = (mode == 0) ? (z == 0 ? X0 : (z == 1 ? X1 : X2)) : X0;
  const unsigned short* Wh = (mode == 0) ? wb + (size_t)z * 6 * (1u << 20) : wb;
  const unsigned short* Wl = Wh + 3 * (1u << 20);

  const int wm = (wave >> 1) * 64, wn = (wave & 1) * 64;
  const int mrow = lane & 15, quad = lane >> 4;
  const int r16 = lane >> 2, cs = lane & 3;
  const int src_chunk = (cs - (r16 >> 1)) & 3;           // B global-side swizzle
  const int bswz = ((quad + (mrow >> 1)) & 3) * 8;       // B frag-read swizzle

  f32x4 acc[4][4] = {};

  const int kbeg = (mode == 0) ? 0 : z;
  const int kend = (mode == 0) ? 3 : z + 1;
  for (int koff = kbeg; koff < kend; ++koff) {
    const bool edge_lo = (l0v == 0 && koff == 0);
    const bool edge_hi = (l0v == NL - 128 && koff == 2);
    for (int i0 = 0; i0 < ND; i0 += 32) {
      // ---- B staging: async 16B, wave covers segments 2w, 2w+1
#pragma unroll
      for (int s = 0; s < 2; ++s) {
        const int seg = wave * 2 + s;
        const size_t goff = ((size_t)koff << 20) +
                            (size_t)(n0 + seg * 16 + r16) * ND + i0 + src_chunk * 8;
        __builtin_amdgcn_global_load_lds(
            (const __attribute__((address_space(1))) unsigned int*)(Wh + goff),
            (__attribute__((address_space(3))) unsigned int*)&Bh[seg * 512], 16, 0, 0);
        __builtin_amdgcn_global_load_lds(
            (const __attribute__((address_space(1))) unsigned int*)(Wl + goff),
            (__attribute__((address_space(3))) unsigned int*)&Bl[seg * 512], 16, 0, 0);
      }
      // ---- A staging: fp32 async 16B, row-chunk swizzle (sir - row&7)
#pragma unroll
      for (int j = 0; j < 4; ++j) {
        const int s = (wave * 4 + j) * 64 + lane;
        const int row = s >> 3, sir = s & 7;
        const int chunk = (sir - (row & 7)) & 7;
        int l = l0v + row + koff - 1;
        l = (l < 0) ? 0 : (l > NL - 1 ? NL - 1 : l);    // clamp; edge rows zero-fixed below
        const float* gp = X + ((size_t)(b << 10) + l) * ND + i0 + chunk * 4;
        __builtin_amdgcn_global_load_lds(
            (const __attribute__((address_space(1))) unsigned int*)gp,
            (__attribute__((address_space(3))) unsigned int*)&Af[(wave * 4 + j) * 256],
            16, 0, 0);
      }
      __syncthreads();
      if (edge_lo || edge_hi) {              // block-uniform, 2 blocks per z only
        const int er = edge_lo ? 0 : 127;
        if (tid < 8) *(float4*)&Af[er * 32 + tid * 4] = make_float4(0.f, 0.f, 0.f, 0.f);
        __syncthreads();
      }
      // ---- fragments + split + MFMA (48/wave/step)
      bf16x8 ah[4], al[4];
#pragma unroll
      for (int mi = 0; mi < 4; ++mi) {
        const int row = wm + mi * 16 + mrow, r7 = row & 7;
        float4 fa = *(const float4*)&Af[row * 32 + (((quad * 2) + r7) & 7) * 4];
        float4 fb = *(const float4*)&Af[row * 32 + (((quad * 2 + 1) + r7) & 7) * 4];
        split8(fa, fb, &ah[mi], &al[mi]);
      }
#pragma unroll
      for (int ni = 0; ni < 4; ++ni) {
        const int brow = wn + ni * 16 + mrow;
        bf16x8 bh = *(const bf16x8*)&Bh[brow * 32 + bswz];
        bf16x8 bl = *(const bf16x8*)&Bl[brow * 32 + bswz];
#pragma unroll
        for (int mi = 0; mi < 4; ++mi) {
          acc[mi][ni] = __builtin_amdgcn_mfma_f32_16x16x32_bf16(ah[mi], bh, acc[mi][ni], 0, 0, 0);
          acc[mi][ni] = __builtin_amdgcn_mfma_f32_16x16x32_bf16(ah[mi], bl, acc[mi][ni], 0, 0, 0);
          acc[mi][ni] = __builtin_amdgcn_mfma_f32_16x16x32_bf16(al[mi], bh, acc[mi][ni], 0, 0, 0);
        }
      }
      __syncthreads();
    }
  }

  // ---- epilogue
  if (mode == 0) {
    float* Y = (z == 0) ? Y0 : (z == 1 ? Y1 : Y2);
    const float* bias = (z == 0) ? b0 : (z == 1 ? b1 : b2);
#pragma unroll
    for (int ni = 0; ni < 4; ++ni) {
      const int n = n0 + wn + ni * 16 + mrow;
      const float bv = bias[n];
      const int h = n >> 6, dd = n & 63;
#pragma unroll
      for (int mi = 0; mi < 4; ++mi) {
        const int mbase = m0 + wm + mi * 16 + quad * 4;
        f32x4 v = acc[mi][ni];
#pragma unroll
        for (int r = 0; r < 4; ++r) {
          const int l = (mbase + r) & (NL - 1);
          Y[(((size_t)b * NH + h) * NL + l) * HD + dd] = v[r] + bv;
        }
      }
    }
  } else {
    float* P = Y0 + (size_t)z * ((size_t)NB * NL * ND);
#pragma unroll
    for (int ni = 0; ni < 4; ++ni) {
      const int n = n0 + wn + ni * 16 + mrow;
#pragma unroll
      for (int mi = 0; mi < 4; ++mi) {
        const int mbase = m0 + wm + mi * 16 + quad * 4;
        f32x4 v = acc[mi][ni];
#pragma unroll
        for (int r = 0; r < 4; ++r) {
          const int l = (mbase + r) & (NL - 1);
          P[((size_t)(b << 10) + l) * ND + n] = v[r];
        }
      }
    }
  }
}

// ---------------- reduce: out = P0 + P1 + P2 + bias ----------------
__global__ __launch_bounds__(256) void reduce_kernel(
    const float* __restrict__ P, const float* __restrict__ bias, float* __restrict__ out)
{
  const size_t S = (size_t)NB * NL * ND;
  const size_t idx = ((size_t)blockIdx.x * 256 + threadIdx.x) * 4;
  const int n = (int)(idx & (ND - 1));
  float4 p0 = *(const float4*)&P[idx];
  float4 p1 = *(const float4*)&P[idx + S];
  float4 p2 = *(const float4*)&P[idx + 2 * S];
  float4 bv = *(const float4*)&bias[n];
  float4 r;
  r.x = p0.x + p1.x + p2.x + bv.x;
  r.y = p0.y + p1.y + p2.y + bv.y;
  r.z = p0.z + p1.z + p2.z + bv.z;
  r.w = p0.w + p1.w + p2.w + bv.w;
  *(float4*)&out[idx] = r;
}

// ---------------- fused attention (flash-style, fp32) — unchanged ----------------
__global__ __launch_bounds__(256) void attn_kernel(
    const float* __restrict__ qT, const float* __restrict__ kT,
    const float* __restrict__ vT, const int* __restrict__ kpm,
    const float* __restrict__ amask, float* __restrict__ AO)
{
  const int m0 = blockIdx.x * 64;
  const int h  = blockIdx.y;
  const int b  = blockIdx.z;
  __shared__ __align__(16) float Qs[64 * 68];
  __shared__ __align__(16) float KPs[64 * 68];
  __shared__ __align__(16) float Vs[64 * 68];
  __shared__ float alphaS[64];
  __shared__ float rowlS[64];
  const int tid = threadIdx.x;
  const int ty = tid >> 4, tx = tid & 15;
  const float scale = 0.125f;
  const size_t baseQ = (((size_t)b * NH + h) * NL) * HD;

  const int rrow = tid >> 4;
  const int rcol = (tid & 15) << 2;

#pragma unroll
  for (int rr = 0; rr < 4; ++rr) {
    int r = rrow + rr * 16;
    float4 v = *(const float4*)&qT[baseQ + (size_t)(m0 + r) * HD + rcol];
    Qs[(rcol + 0) * 68 + r] = v.x;
    Qs[(rcol + 1) * 68 + r] = v.y;
    Qs[(rcol + 2) * 68 + r] = v.z;
    Qs[(rcol + 3) * 68 + r] = v.w;
  }

  float acc[4][4] = {};
  float m_r = -INFINITY, l_r = 0.0f;

  for (int n0 = 0; n0 < NL; n0 += 64) {
#pragma unroll
    for (int rr = 0; rr < 4; ++rr) {
      int c = rrow + rr * 16;
      float4 kv = *(const float4*)&kT[baseQ + (size_t)(n0 + c) * HD + rcol];
      KPs[(rcol + 0) * 68 + c] = kv.x;
      KPs[(rcol + 1) * 68 + c] = kv.y;
      KPs[(rcol + 2) * 68 + c] = kv.z;
      KPs[(rcol + 3) * 68 + c] = kv.w;
      float4 vv = *(const float4*)&vT[baseQ + (size_t)(n0 + c) * HD + rcol];
      *(float4*)&Vs[c * 68 + rcol] = vv;
    }
    __syncthreads();

    float s[4][4] = {};
#pragma unroll 8
    for (int dd = 0; dd < 64; ++dd) {
      float4 qa = *(const float4*)&Qs[dd * 68 + ty * 4];
      float4 ka = *(const float4*)&KPs[dd * 68 + tx * 4];
      float qv[4] = {qa.x, qa.y, qa.z, qa.w};
      float kv[4] = {ka.x, ka.y, ka.z, ka.w};
#pragma unroll
      for (int i = 0; i < 4; ++i)
#pragma unroll
        for (int j = 0; j < 4; ++j) s[i][j] += qv[i] * kv[j];
    }
    __syncthreads();

#pragma unroll
    for (int i = 0; i < 4; ++i) {
      int gr = m0 + ty * 4 + i;
#pragma unroll
      for (int j = 0; j < 4; ++j) {
        int gc = n0 + tx * 4 + j;
        float val = s[i][j] * scale + amask[(size_t)gr * NL + gc];
        if (kpm[b * NL + gc] != 0) val = -INFINITY;
        KPs[(tx * 4 + j) * 68 + (ty * 4 + i)] = val;
      }
    }
    __syncthreads();

    if (tid < 64) {
      const int r = tid;
      float tmax = -INFINITY;
      for (int j = 0; j < 64; ++j) tmax = fmaxf(tmax, KPs[j * 68 + r]);
      float newm = fmaxf(m_r, tmax);
      float alpha;
      float rowsum = 0.0f;
      if (newm == -INFINITY) {
        alpha = 1.0f;
        for (int j = 0; j < 64; ++j) KPs[j * 68 + r] = 0.0f;
      } else {
        alpha = __expf(m_r - newm);
        for (int j = 0; j < 64; ++j) {
          float p = __expf(KPs[j * 68 + r] - newm);
          KPs[j * 68 + r] = p;
          rowsum += p;
        }
      }
      m_r = newm;
      l_r = l_r * alpha + rowsum;
      alphaS[r] = alpha;
    }
    __syncthreads();

#pragma unroll
    for (int i = 0; i < 4; ++i) {
      float a = alphaS[ty * 4 + i];
#pragma unroll
      for (int j = 0; j < 4; ++j) acc[i][j] *= a;
    }
#pragma unroll 8
    for (int jk = 0; jk < 64; ++jk) {
      float4 pa = *(const float4*)&KPs[jk * 68 + ty * 4];
      float4 va = *(const float4*)&Vs[jk * 68 + tx * 4];
      float pv[4] = {pa.x, pa.y, pa.z, pa.w};
      float vv[4] = {va.x, va.y, va.z, va.w};
#pragma unroll
      for (int i = 0; i < 4; ++i)
#pragma unroll
        for (int j = 0; j < 4; ++j) acc[i][j] += pv[i] * vv[j];
    }
    __syncthreads();
  }

  if (tid < 64) rowlS[tid] = l_r;
  __syncthreads();

#pragma unroll
  for (int i = 0; i < 4; ++i) {
    int gr = m0 + ty * 4 + i;
    float inv = 1.0f / rowlS[ty * 4 + i];
    float4 v;
    v.x = acc[i][0] * inv;
    v.y = acc[i][1] * inv;
    v.z = acc[i][2] * inv;
    v.w = acc[i][3] * inv;
    *(float4*)&AO[((size_t)(b << 10) + gr) * ND + h * HD + tx * 4] = v;
  }
}

// ---------------- launch ----------------
extern "C" void kernel_launch(void* const* d_in, const int* in_sizes, int n_in,
                              void* d_out, int out_size, void* d_ws, size_t ws_size,
                              hipStream_t stream) {
  (void)in_sizes; (void)n_in; (void)out_size; (void)ws_size;
  const float* query = (const float*)d_in[0];
  const float* key_  = (const float*)d_in[1];
  const float* value = (const float*)d_in[2];
  const int*   kpm   = (const int*)d_in[3];
  const float* amask = (const float*)d_in[4];
  const float* q_w = (const float*)d_in[5];
  const float* q_b = (const float*)d_in[6];
  const float* k_w = (const float*)d_in[7];
  const float* k_b = (const float*)d_in[8];
  const float* v_w = (const float*)d_in[9];
  const float* v_b = (const float*)d_in[10];
  const float* o_w = (const float*)d_in[11];
  const float* o_b = (const float*)d_in[12];
  float* out = (float*)d_out;

  // ws (100,663,296 B total, same as R1-R3):
  //   [0, 50.33 MB): Wb (4 tensors, hi/lo bf16)
  //   [50.33, 100.66): qT/kT/vT fp32  -> reused as P0/P1/P2 after attention
  //   AO fp32 aliases [0, 16.78 MB) over dead Wb_q/part of Wb_k (Wb_o untouched)
  unsigned short* Wb = (unsigned short*)d_ws;
  float* qT = (float*)((char*)d_ws + (size_t)50331648);
  float* kT = qT + (size_t)NB * NL * ND;
  float* vT = kT + (size_t)NB * NL * ND;
  float* P  = qT;
  float* AO = (float*)d_ws;

  wcvt_kernel<<<dim3(1024, 4), 256, 0, stream>>>(q_w, k_w, v_w, o_w, Wb);
  conv_mfma2<<<dim3(8, 32, 3), 256, 0, stream>>>(
      query, key_, value, Wb, q_b, k_b, v_b, qT, kT, vT, 0);
  attn_kernel<<<dim3(16, 16, 4), 256, 0, stream>>>(qT, kT, vT, kpm, amask, AO);
  conv_mfma2<<<dim3(8, 32, 3), 256, 0, stream>>>(
      AO, AO, AO, Wb + (size_t)3 * 6 * (1u << 20), o_b, o_b, o_b, P, P, P, 1);
  reduce_kernel<<<4096, 256, 0, stream>>>(P, o_b, out);
}

// Round 5
// 504.724 us; speedup vs baseline: 4.1724x; 1.5966x over previous
//
#include <hip/hip_runtime.h>
#include <math.h>

#define NB 4
#define NL 1024
#define ND 1024
#define NH 16
#define HD 64

typedef __attribute__((ext_vector_type(8))) short bf16x8;
typedef __attribute__((ext_vector_type(4))) float f32x4;

static __device__ __forceinline__ unsigned short f32_to_bf16(float f) {
  unsigned u = __float_as_uint(f);
  u += 0x7FFFu + ((u >> 16) & 1u);   // RNE
  return (unsigned short)(u >> 16);
}
static __device__ __forceinline__ float bf16_to_f32(unsigned short s) {
  return __uint_as_float(((unsigned)s) << 16);
}

// trunc-split 8 fp32 -> hi bf16x8 + lo bf16x8 (residual trunc). err ~2^-16 rel.
static __device__ __forceinline__ void split8(float4 a, float4 b, bf16x8* hi, bf16x8* lo) {
  unsigned u[8] = {__float_as_uint(a.x), __float_as_uint(a.y),
                   __float_as_uint(a.z), __float_as_uint(a.w),
                   __float_as_uint(b.x), __float_as_uint(b.y),
                   __float_as_uint(b.z), __float_as_uint(b.w)};
  union { unsigned p[4]; bf16x8 v; } H, L;
#pragma unroll
  for (int p = 0; p < 4; ++p) {
    unsigned u0 = u[2 * p], u1 = u[2 * p + 1];
    H.p[p] = __builtin_amdgcn_perm(u1, u0, 0x07060302u);
    unsigned l0 = __float_as_uint(__uint_as_float(u0) - __uint_as_float(u0 & 0xFFFF0000u));
    unsigned l1 = __float_as_uint(__uint_as_float(u1) - __uint_as_float(u1 & 0xFFFF0000u));
    L.p[p] = __builtin_amdgcn_perm(l1, l0, 0x07060302u);
  }
  *hi = H.v; *lo = L.v;
}

// ---------------- weight convert (+ zero the amask flag) ----------------
__global__ __launch_bounds__(256) void wcvt_kernel(
    const float* __restrict__ w0, const float* __restrict__ w1,
    const float* __restrict__ w2, const float* __restrict__ w3,
    unsigned short* __restrict__ wb, int* __restrict__ flag)
{
  if (blockIdx.x == 0 && blockIdx.y == 0 && threadIdx.x == 0) flag[0] = 0;
  const int t = blockIdx.y;
  const int o = blockIdx.x;
  const float* w = (t == 0) ? w0 : (t == 1) ? w1 : (t == 2) ? w2 : w3;
  unsigned short* hi = wb + (size_t)t * 6 * (1u << 20);
  unsigned short* lo = hi + 3 * (1u << 20);
  const int tid = threadIdx.x;
  float v[12];
  const float* src = w + (size_t)o * (ND * 3) + tid * 12;
#pragma unroll
  for (int j = 0; j < 3; ++j) {
    float4 f = *(const float4*)(src + j * 4);
    v[j * 4 + 0] = f.x; v[j * 4 + 1] = f.y; v[j * 4 + 2] = f.z; v[j * 4 + 3] = f.w;
  }
#pragma unroll
  for (int k = 0; k < 3; ++k) {
    unsigned short hh[4], ll[4];
#pragma unroll
    for (int ii = 0; ii < 4; ++ii) {
      float x = v[ii * 3 + k];
      unsigned short h = f32_to_bf16(x);
      float r = x - bf16_to_f32(h);
      hh[ii] = h; ll[ii] = f32_to_bf16(r);
    }
    size_t dst = (size_t)k * (ND * ND) + (size_t)o * ND + tid * 4;
    *(ushort4*)&hi[dst] = make_ushort4(hh[0], hh[1], hh[2], hh[3]);
    *(ushort4*)&lo[dst] = make_ushort4(ll[0], ll[1], ll[2], ll[3]);
  }
}

// ---------------- amask zero-scan ----------------
__global__ __launch_bounds__(256) void amask_scan(
    const float* __restrict__ a, int* __restrict__ flag)
{
  size_t i = ((size_t)blockIdx.x * 256 + threadIdx.x) * 4;
  float4 v = *(const float4*)&a[i];
  if (v.x != 0.f || v.y != 0.f || v.z != 0.f || v.w != 0.f) atomicOr(flag, 1);
}

// ---------------- conv-as-GEMM (unchanged from R4) ----------------
__global__ __launch_bounds__(256, 3) void conv_mfma2(
    const float* X0, const float* X1, const float* X2,
    const unsigned short* __restrict__ wb,
    const float* b0, const float* b1, const float* b2,
    float* Y0, float* Y1, float* Y2, int mode)
{
  __shared__ float Af[128 * 32];
  __shared__ unsigned short Bh[128 * 32];
  __shared__ unsigned short Bl[128 * 32];

  const int tid = threadIdx.x, lane = tid & 63, wave = tid >> 6;
  const int lin = blockIdx.x + 8 * (blockIdx.y + 32 * blockIdx.z);
  const int g = lin & 7, t = lin >> 3;
  const int nb = (g & 3) * 2 + (t & 1);
  const int mb = (g >> 2) * 16 + ((t >> 1) & 15);
  const int z  = t >> 5;
  const int n0 = nb * 128, m0 = mb * 128;
  const int b = m0 >> 10, l0v = m0 & (NL - 1);

  const float* X = (mode == 0) ? (z == 0 ? X0 : (z == 1 ? X1 : X2)) : X0;
  const unsigned short* Wh = (mode == 0) ? wb + (size_t)z * 6 * (1u << 20) : wb;
  const unsigned short* Wl = Wh + 3 * (1u << 20);

  const int wm = (wave >> 1) * 64, wn = (wave & 1) * 64;
  const int mrow = lane & 15, quad = lane >> 4;
  const int r16 = lane >> 2, cs = lane & 3;
  const int src_chunk = (cs - (r16 >> 1)) & 3;
  const int bswz = ((quad + (mrow >> 1)) & 3) * 8;

  f32x4 acc[4][4] = {};

  const int kbeg = (mode == 0) ? 0 : z;
  const int kend = (mode == 0) ? 3 : z + 1;
  for (int koff = kbeg; koff < kend; ++koff) {
    const bool edge_lo = (l0v == 0 && koff == 0);
    const bool edge_hi = (l0v == NL - 128 && koff == 2);
    for (int i0 = 0; i0 < ND; i0 += 32) {
#pragma unroll
      for (int s = 0; s < 2; ++s) {
        const int seg = wave * 2 + s;
        const size_t goff = ((size_t)koff << 20) +
                            (size_t)(n0 + seg * 16 + r16) * ND + i0 + src_chunk * 8;
        __builtin_amdgcn_global_load_lds(
            (const __attribute__((address_space(1))) unsigned int*)(Wh + goff),
            (__attribute__((address_space(3))) unsigned int*)&Bh[seg * 512], 16, 0, 0);
        __builtin_amdgcn_global_load_lds(
            (const __attribute__((address_space(1))) unsigned int*)(Wl + goff),
            (__attribute__((address_space(3))) unsigned int*)&Bl[seg * 512], 16, 0, 0);
      }
#pragma unroll
      for (int j = 0; j < 4; ++j) {
        const int s = (wave * 4 + j) * 64 + lane;
        const int row = s >> 3, sir = s & 7;
        const int chunk = (sir - (row & 7)) & 7;
        int l = l0v + row + koff - 1;
        l = (l < 0) ? 0 : (l > NL - 1 ? NL - 1 : l);
        const float* gp = X + ((size_t)(b << 10) + l) * ND + i0 + chunk * 4;
        __builtin_amdgcn_global_load_lds(
            (const __attribute__((address_space(1))) unsigned int*)gp,
            (__attribute__((address_space(3))) unsigned int*)&Af[(wave * 4 + j) * 256],
            16, 0, 0);
      }
      __syncthreads();
      if (edge_lo || edge_hi) {
        const int er = edge_lo ? 0 : 127;
        if (tid < 8) *(float4*)&Af[er * 32 + tid * 4] = make_float4(0.f, 0.f, 0.f, 0.f);
        __syncthreads();
      }
      bf16x8 ah[4], al[4];
#pragma unroll
      for (int mi = 0; mi < 4; ++mi) {
        const int row = wm + mi * 16 + mrow, r7 = row & 7;
        float4 fa = *(const float4*)&Af[row * 32 + (((quad * 2) + r7) & 7) * 4];
        float4 fb = *(const float4*)&Af[row * 32 + (((quad * 2 + 1) + r7) & 7) * 4];
        split8(fa, fb, &ah[mi], &al[mi]);
      }
#pragma unroll
      for (int ni = 0; ni < 4; ++ni) {
        const int brow = wn + ni * 16 + mrow;
        bf16x8 bh = *(const bf16x8*)&Bh[brow * 32 + bswz];
        bf16x8 bl = *(const bf16x8*)&Bl[brow * 32 + bswz];
#pragma unroll
        for (int mi = 0; mi < 4; ++mi) {
          acc[mi][ni] = __builtin_amdgcn_mfma_f32_16x16x32_bf16(ah[mi], bh, acc[mi][ni], 0, 0, 0);
          acc[mi][ni] = __builtin_amdgcn_mfma_f32_16x16x32_bf16(ah[mi], bl, acc[mi][ni], 0, 0, 0);
          acc[mi][ni] = __builtin_amdgcn_mfma_f32_16x16x32_bf16(al[mi], bh, acc[mi][ni], 0, 0, 0);
        }
      }
      __syncthreads();
    }
  }

  if (mode == 0) {
    float* Y = (z == 0) ? Y0 : (z == 1 ? Y1 : Y2);
    const float* bias = (z == 0) ? b0 : (z == 1 ? b1 : b2);
#pragma unroll
    for (int ni = 0; ni < 4; ++ni) {
      const int n = n0 + wn + ni * 16 + mrow;
      const float bv = bias[n];
      const int h = n >> 6, dd = n & 63;
#pragma unroll
      for (int mi = 0; mi < 4; ++mi) {
        const int mbase = m0 + wm + mi * 16 + quad * 4;
        f32x4 v = acc[mi][ni];
#pragma unroll
        for (int r = 0; r < 4; ++r) {
          const int l = (mbase + r) & (NL - 1);
          Y[(((size_t)b * NH + h) * NL + l) * HD + dd] = v[r] + bv;
        }
      }
    }
  } else {
    float* P = Y0 + (size_t)z * ((size_t)NB * NL * ND);
#pragma unroll
    for (int ni = 0; ni < 4; ++ni) {
      const int n = n0 + wn + ni * 16 + mrow;
#pragma unroll
      for (int mi = 0; mi < 4; ++mi) {
        const int mbase = m0 + wm + mi * 16 + quad * 4;
        f32x4 v = acc[mi][ni];
#pragma unroll
        for (int r = 0; r < 4; ++r) {
          const int l = (mbase + r) & (NL - 1);
          P[((size_t)(b << 10) + l) * ND + n] = v[r];
        }
      }
    }
  }
}

// ---------------- reduce (unchanged) ----------------
__global__ __launch_bounds__(256) void reduce_kernel(
    const float* __restrict__ P, const float* __restrict__ bias, float* __restrict__ out)
{
  const size_t S = (size_t)NB * NL * ND;
  const size_t idx = ((size_t)blockIdx.x * 256 + threadIdx.x) * 4;
  const int n = (int)(idx & (ND - 1));
  float4 p0 = *(const float4*)&P[idx];
  float4 p1 = *(const float4*)&P[idx + S];
  float4 p2 = *(const float4*)&P[idx + 2 * S];
  float4 bv = *(const float4*)&bias[n];
  float4 r;
  r.x = p0.x + p1.x + p2.x + bv.x;
  r.y = p0.y + p1.y + p2.y + bv.y;
  r.z = p0.z + p1.z + p2.z + bv.z;
  r.w = p0.w + p1.w + p2.w + bv.w;
  *(float4*)&out[idx] = r;
}

// ---------------- MFMA flash attention ----------------
// St = K·Q^T (C-layout col = q-row), softmax in registers, O^T = V^T·P^T.
__global__ __launch_bounds__(256, 3) void attn_mfma(
    const float* __restrict__ qT, const float* __restrict__ kT,
    const float* __restrict__ vT, const int* __restrict__ kpm,
    const float* __restrict__ amask, const int* __restrict__ aflagp,
    float* __restrict__ AO)
{
  // LDS: Kh | Kl | Vt, each 64 rows x 72 ushort (stride 72 = 144B, 16B-aligned).
  // Q staged temporarily in Kh/Kl before the K-loop.
  __shared__ __align__(16) unsigned short S[3 * 64 * 72];
  unsigned short* Kh = S;
  unsigned short* Kl = S + 4608;
  unsigned short* Vt = S + 2 * 4608;

  const int tid = threadIdx.x, lane = tid & 63, wave = tid >> 6;
  const int c = lane & 15, quad = lane >> 4;
  const int lin = blockIdx.x;
  const int bh = (lin & 7) + 8 * (lin >> 7);      // same bh -> same XCD (lin%8)
  const int mt = (lin >> 3) & 15;
  const int b = bh >> 4;
  const int m0 = mt * 64;
  const size_t base = (size_t)bh * NL * HD;
  const int aflag = *aflagp;
  const int mrow = wave * 16 + c;                 // this lane's q-row (local)
  const int gm = m0 + mrow;

  const int sr = tid >> 2, scq = tid & 3;         // staging thread -> (row, quarter)

  // ---- stage Q (x0.125) split hi/lo into Kh/Kl ----
#pragma unroll
  for (int ii = 0; ii < 2; ++ii) {
    const int c8 = scq * 2 + ii;
    const float* gp = &qT[base + (size_t)(m0 + sr) * HD + c8 * 8];
    float4 a = *(const float4*)gp, bb = *(const float4*)(gp + 4);
    a.x *= 0.125f; a.y *= 0.125f; a.z *= 0.125f; a.w *= 0.125f;
    bb.x *= 0.125f; bb.y *= 0.125f; bb.z *= 0.125f; bb.w *= 0.125f;
    bf16x8 hi, lo; split8(a, bb, &hi, &lo);
    const int cso = ((c8 + sr) & 7) * 8;
    *(bf16x8*)&Kh[sr * 72 + cso] = hi;
    *(bf16x8*)&Kl[sr * 72 + cso] = lo;
  }
  __syncthreads();
  // ---- Q B-frags to registers ----
  bf16x8 qbh[2], qbl[2];
#pragma unroll
  for (int kb = 0; kb < 2; ++kb) {
    const int cso = ((kb * 4 + quad + mrow) & 7) * 8;
    qbh[kb] = *(const bf16x8*)&Kh[mrow * 72 + cso];
    qbl[kb] = *(const bf16x8*)&Kl[mrow * 72 + cso];
  }

  f32x4 acc[4] = {};            // O^T frags: dd = ddf*16 + quad*4 + r, col = q-row
  float m_r = -INFINITY, l_r = 0.0f;

  for (int n0t = 0; n0t < NL; n0t += 64) {
    __syncthreads();            // frags/compute of prev tile done before restaging

    // masks for this lane's 16 score slots (n = nf*16 + quad*4 + r)
    float mval[4][4];
#pragma unroll
    for (int nf = 0; nf < 4; ++nf)
#pragma unroll
      for (int r = 0; r < 4; ++r) {
        const int gn = n0t + nf * 16 + quad * 4 + r;
        const bool pm = kpm[b * NL + gn] != 0;
        float am = 0.f;
        if (aflag) am = amask[(size_t)gm * NL + gn];
        mval[nf][r] = pm ? -INFINITY : am;
      }

    // ---- stage K (split) and V^T (bf16) ----
#pragma unroll
    for (int ii = 0; ii < 2; ++ii) {
      const int c8 = scq * 2 + ii;
      const float* gp = &kT[base + (size_t)(n0t + sr) * HD + c8 * 8];
      float4 a = *(const float4*)gp, bb = *(const float4*)(gp + 4);
      bf16x8 hi, lo; split8(a, bb, &hi, &lo);
      const int cso = ((c8 + sr) & 7) * 8;
      *(bf16x8*)&Kh[sr * 72 + cso] = hi;
      *(bf16x8*)&Kl[sr * 72 + cso] = lo;

      const float* gv = &vT[base + (size_t)(n0t + sr) * HD + c8 * 8];
      float4 va = *(const float4*)gv, vb = *(const float4*)(gv + 4);
      float ve[8] = {va.x, va.y, va.z, va.w, vb.x, vb.y, vb.z, vb.w};
#pragma unroll
      for (int e = 0; e < 8; ++e) {
        const int dd = c8 * 8 + e;
        Vt[dd * 72 + (((sr >> 3) + dd) & 7) * 8 + (sr & 7)] = f32_to_bf16(ve[e]);
      }
    }
    __syncthreads();

    // ---- St = K·Q^T (3-MFMA split) ----
    f32x4 sa[4] = {};
#pragma unroll
    for (int kb = 0; kb < 2; ++kb)
#pragma unroll
      for (int nf = 0; nf < 4; ++nf) {
        const int row = nf * 16 + c;
        const int cso = ((kb * 4 + quad + row) & 7) * 8;
        bf16x8 kah = *(const bf16x8*)&Kh[row * 72 + cso];
        bf16x8 kal = *(const bf16x8*)&Kl[row * 72 + cso];
        sa[nf] = __builtin_amdgcn_mfma_f32_16x16x32_bf16(kah, qbh[kb], sa[nf], 0, 0, 0);
        sa[nf] = __builtin_amdgcn_mfma_f32_16x16x32_bf16(kah, qbl[kb], sa[nf], 0, 0, 0);
        sa[nf] = __builtin_amdgcn_mfma_f32_16x16x32_bf16(kal, qbh[kb], sa[nf], 0, 0, 0);
      }

    // ---- online softmax in registers ----
    float p[4][4];
    float tmax = -INFINITY;
#pragma unroll
    for (int nf = 0; nf < 4; ++nf)
#pragma unroll
      for (int r = 0; r < 4; ++r) {
        float s = sa[nf][r] + mval[nf][r];
        p[nf][r] = s;
        tmax = fmaxf(tmax, s);
      }
    tmax = fmaxf(tmax, __shfl_xor(tmax, 16));
    tmax = fmaxf(tmax, __shfl_xor(tmax, 32));
    const float newm = fmaxf(m_r, tmax);
    const float msafe = (newm == -INFINITY) ? 0.f : newm;
    const float alpha = __expf(m_r - msafe);
    float rs = 0.f;
#pragma unroll
    for (int nf = 0; nf < 4; ++nf)
#pragma unroll
      for (int r = 0; r < 4; ++r) {
        float e = __expf(p[nf][r] - msafe);
        p[nf][r] = e;
        rs += e;
      }
    rs += __shfl_xor(rs, 16);
    rs += __shfl_xor(rs, 32);
    l_r = l_r * alpha + rs;
    m_r = newm;
#pragma unroll
    for (int df = 0; df < 4; ++df) {
      acc[df][0] *= alpha; acc[df][1] *= alpha;
      acc[df][2] *= alpha; acc[df][3] *= alpha;
    }

    // ---- pack P to bf16 dwords: q16[nf][w] = (p[2w+1]<<16)|p[2w] ----
    unsigned q16[4][2];
#pragma unroll
    for (int nf = 0; nf < 4; ++nf)
#pragma unroll
      for (int w = 0; w < 2; ++w)
        q16[nf][w] = (unsigned)f32_to_bf16(p[nf][2 * w]) |
                     ((unsigned)f32_to_bf16(p[nf][2 * w + 1]) << 16);

    // ---- O^T += V^T · P^T ----
#pragma unroll
    for (int kb = 0; kb < 2; ++kb) {
      union { unsigned d[4]; bf16x8 v; } pb;
#pragma unroll
      for (int w = 0; w < 4; ++w) {
        const int addr = ((((quad & 1) * 2 + (w >> 1)) * 16 + c) << 2);
        unsigned v0 = __builtin_amdgcn_ds_bpermute(addr, (int)q16[2 * kb][w & 1]);
        unsigned v1 = __builtin_amdgcn_ds_bpermute(addr, (int)q16[2 * kb + 1][w & 1]);
        pb.d[w] = (quad >> 1) ? v1 : v0;
      }
#pragma unroll
      for (int df = 0; df < 4; ++df) {
        const int row = df * 16 + c;
        const int cso = ((kb * 4 + quad + row) & 7) * 8;
        bf16x8 va = *(const bf16x8*)&Vt[row * 72 + cso];
        acc[df] = __builtin_amdgcn_mfma_f32_16x16x32_bf16(va, pb.v, acc[df], 0, 0, 0);
      }
    }
  }

  // ---- epilogue: transpose O^T -> O via LDS, coalesced store ----
  __syncthreads();
  const float inv = 1.0f / l_r;
  float* Ob = (float*)S + wave * (16 * 68);
#pragma unroll
  for (int df = 0; df < 4; ++df)
#pragma unroll
    for (int r = 0; r < 4; ++r)
      Ob[c * 68 + df * 16 + quad * 4 + r] = acc[df][r] * inv;
  __syncthreads();
  const int mr2 = lane >> 2, cq2 = lane & 3;
  const int h = bh & 15;
#pragma unroll
  for (int ii = 0; ii < 4; ++ii) {
    const int chunk = cq2 * 4 + ii;
    float4 v = *(const float4*)&Ob[mr2 * 68 + chunk * 4];
    *(float4*)&AO[((size_t)(b << 10) + (m0 + wave * 16 + mr2)) * ND +
                  h * HD + chunk * 4] = v;
  }
}

// ---------------- launch ----------------
extern "C" void kernel_launch(void* const* d_in, const int* in_sizes, int n_in,
                              void* d_out, int out_size, void* d_ws, size_t ws_size,
                              hipStream_t stream) {
  (void)in_sizes; (void)n_in; (void)out_size; (void)ws_size;
  const float* query = (const float*)d_in[0];
  const float* key_  = (const float*)d_in[1];
  const float* value = (const float*)d_in[2];
  const int*   kpm   = (const int*)d_in[3];
  const float* amask = (const float*)d_in[4];
  const float* q_w = (const float*)d_in[5];
  const float* q_b = (const float*)d_in[6];
  const float* k_w = (const float*)d_in[7];
  const float* k_b = (const float*)d_in[8];
  const float* v_w = (const float*)d_in[9];
  const float* v_b = (const float*)d_in[10];
  const float* o_w = (const float*)d_in[11];
  const float* o_b = (const float*)d_in[12];
  float* out = (float*)d_out;

  unsigned short* Wb = (unsigned short*)d_ws;
  float* qT = (float*)((char*)d_ws + (size_t)50331648);
  float* kT = qT + (size_t)NB * NL * ND;
  float* vT = kT + (size_t)NB * NL * ND;
  float* P  = qT;
  float* AO = (float*)d_ws;
  int* flag = (int*)d_out;   // dead until reduce overwrites it

  wcvt_kernel<<<dim3(1024, 4), 256, 0, stream>>>(q_w, k_w, v_w, o_w, Wb, flag);
  amask_scan<<<1024, 256, 0, stream>>>(amask, flag);
  conv_mfma2<<<dim3(8, 32, 3), 256, 0, stream>>>(
      query, key_, value, Wb, q_b, k_b, v_b, qT, kT, vT, 0);
  attn_mfma<<<1024, 256, 0, stream>>>(qT, kT, vT, kpm, amask, flag, AO);
  conv_mfma2<<<dim3(8, 32, 3), 256, 0, stream>>>(
      AO, AO, AO, Wb + (size_t)3 * 6 * (1u << 20), o_b, o_b, o_b, P, P, P, 1);
  reduce_kernel<<<4096, 256, 0, stream>>>(P, o_b, out);
}